// Round 13
// baseline (183.187 us; speedup 1.0000x reference)
//
#include <hip/hip_runtime.h>
#include <hip/hip_bf16.h>

#define N_NODES 100000
#define N_PAD   100096      // 782 * 128
#define N_EDGES 1600000
#define OUT_CH  40

#define BSHIFT  6           // 64 nodes per bucket
#define BNODES  64
#define NBUCK   1563        // ceil(N_NODES / 64); covers nodes 0..100031
#define CAPB    1408        // edge capacity per bucket (mean 1024, +12 sigma)
#define EPB     32          // edges per thread in bucket_scatter

typedef unsigned short ushort_t;
typedef unsigned int uint_t;
typedef __attribute__((ext_vector_type(8))) short short8;   // 8 bf16 (4 VGPR)
typedef __attribute__((ext_vector_type(4))) float floatx4;  // MFMA C/D

__device__ inline float blo(uint_t u) { union { uint_t i; float f; } t; t.i = u << 16; return t.f; }
__device__ inline float bhi(uint_t u) { union { uint_t i; float f; } t; t.i = u & 0xffff0000u; return t.f; }
__device__ inline ushort_t f2b(float f) {
    __hip_bfloat16 h = __float2bfloat16(f);
    return *reinterpret_cast<ushort_t*>(&h);
}
__device__ inline uint_t pack2(float a, float b) {
    return (uint_t)f2b(a) | ((uint_t)f2b(b) << 16);
}

// ---------------------------------------------------------------------------
// f32 -> bf16 conversion, 8 elems/thread. Block 0 zeroes the bucket cursors.
// ---------------------------------------------------------------------------
__global__ __launch_bounds__(256) void convert_kernel(
    const float* __restrict__ in, ushort_t* __restrict__ out, int n8,
    int* __restrict__ gcur)
{
    if (blockIdx.x == 0) {
        for (int k = threadIdx.x; k < 2048; k += 256) gcur[k] = 0;
    }
    int i = blockIdx.x * 256 + threadIdx.x;
    if (i >= n8) return;
    const float4 a = *reinterpret_cast<const float4*>(in + (size_t)i * 8);
    const float4 b = *reinterpret_cast<const float4*>(in + (size_t)i * 8 + 4);
    uint4 o;
    o.x = pack2(a.x, a.y);
    o.y = pack2(a.z, a.w);
    o.z = pack2(b.x, b.y);
    o.w = pack2(b.z, b.w);
    *reinterpret_cast<uint4*>(out + (size_t)i * 8) = o;
}

// ---------------------------------------------------------------------------
// Weight pack into MFMA B-fragment layout (bf16). Bases (frag units):
// W1l=0, W1r=512, W2l=1024, W2r=1408 (layer-2 cols padded 40->48, zeros).
// ---------------------------------------------------------------------------
__global__ __launch_bounds__(256) void pack_kernel(
    const float* __restrict__ W1l, const float* __restrict__ W1r,
    const float* __restrict__ W2l, const float* __restrict__ W2r,
    uint4* __restrict__ wp)
{
    int i = blockIdx.x * 256 + threadIdx.x;
    if (i >= 1792) return;
    const float* W; int NC; int off;
    if (i < 512)       { W = W1l; NC = 64; off = i; }
    else if (i < 1024) { W = W1r; NC = 64; off = i - 512; }
    else if (i < 1408) { W = W2l; NC = 40; off = i - 1024; }
    else               { W = W2r; NC = 40; off = i - 1408; }
    int l   = off & 63;
    int kc  = (off >> 6) & 1;
    int nt  = off >> 7;
    int k0  = kc * 32 + ((l >> 4) * 8);
    int col = nt * 16 + (l & 15);
    float v[8];
#pragma unroll
    for (int j = 0; j < 8; ++j)
        v[j] = (col < NC) ? W[(k0 + j) * NC + col] : 0.0f;
    uint4 o;
    o.x = pack2(v[0], v[1]);
    o.y = pack2(v[2], v[3]);
    o.z = pack2(v[4], v[5]);
    o.w = pack2(v[6], v[7]);
    wp[i] = o;
}

// ---------------------------------------------------------------------------
// Partition edges into NBUCK dst-range buckets. Randomness confined to LDS
// histogram atomics; one global atomic per (block,bucket); packed edges:
// src (25b) | local-dst << 25.
// ---------------------------------------------------------------------------
__global__ __launch_bounds__(256) void bucket_scatter(
    const int* __restrict__ src, const int* __restrict__ dst,
    int* __restrict__ gcur, uint_t* __restrict__ bbuf, int n)
{
    __shared__ int lcnt[NBUCK];
    __shared__ int lbase[NBUCK];
    for (int i = threadIdx.x; i < NBUCK; i += 256) lcnt[i] = 0;
    __syncthreads();

    int e0 = blockIdx.x * (256 * EPB) + threadIdx.x;
    int b[EPB], lp[EPB], s[EPB];
#pragma unroll
    for (int u = 0; u < EPB; ++u) {
        int e = e0 + u * 256;
        if (e < n) {
            int d = dst[e];
            s[u] = src[e];
            b[u] = d >> BSHIFT;
            lp[u] = atomicAdd(&lcnt[b[u]], 1);        // pos fits 24 bits
            lp[u] |= (d & (BNODES - 1)) << 24;        // local node in bits 24..29
        } else {
            b[u] = -1;
        }
    }
    __syncthreads();
    for (int i = threadIdx.x; i < NBUCK; i += 256) {
        int c = lcnt[i];
        lbase[i] = (c > 0) ? atomicAdd(&gcur[i], c) : 0;
    }
    __syncthreads();
#pragma unroll
    for (int u = 0; u < EPB; ++u) {
        if (b[u] >= 0) {
            int pos = lbase[b[u]] + (lp[u] & 0x00FFFFFF);
            uint_t ldst = ((uint_t)lp[u]) >> 24;
            if (pos < CAPB)
                bbuf[(size_t)b[u] * CAPB + pos] = (uint_t)s[u] | (ldst << 25);
        }
    }
}

// ---------------------------------------------------------------------------
// Fused per-bucket kernel core (512 threads / 8 waves):
//   A) register-held CSR build (LDS histogram + wave-0 scan + place).
//   B) gather: per wave, 2 passes of 4 nodes ROUND-ROBIN interleaved --
//      each round issues 4 independent 1KB gathers (8 rows x 16B lanes),
//      keeping ~4 chains in flight per wave (MLP is the gather-rate lever).
//   C) mean -> swizzled LDS; dense via MFMA from LDS mean + global self.
// ---------------------------------------------------------------------------
__device__ inline void accum8(float* acc, uint4 v) {
    acc[0] += blo(v.x); acc[1] += bhi(v.x);
    acc[2] += blo(v.y); acc[3] += bhi(v.y);
    acc[4] += blo(v.z); acc[5] += bhi(v.z);
    acc[6] += blo(v.w); acc[7] += bhi(v.w);
}

__device__ inline void build_and_gather(
    const ushort_t* __restrict__ feat, const int* __restrict__ gcur,
    const uint_t* __restrict__ bbuf,
    int* lcsr, int* ldeg, int* lstart, int* lcur, ushort_t* lmean)
{
    int b = blockIdx.x, tid = threadIdx.x;
    int wave = tid >> 6, lane = tid & 63;

    if (tid < BNODES) { ldeg[tid] = 0; lcur[tid] = 0; }
    __syncthreads();

    int ne = gcur[b];
    if (ne > CAPB) ne = CAPB;

    // A1: read edges into registers (<=3 each), histogram degrees in LDS
    uint_t pe[3];
    int npe = 0;
    for (int i = tid; i < ne; i += 512) {
        uint_t p = bbuf[(size_t)b * CAPB + i];
        pe[npe++] = p;
        atomicAdd(&ldeg[p >> 25], 1);
    }
    __syncthreads();

    // A2: wave-0 exclusive scan over 64 degree counts
    if (tid < 64) {
        int v = ldeg[tid];
        int incl = v;
#pragma unroll
        for (int off = 1; off < 64; off <<= 1) {
            int t = __shfl_up(incl, off, 64);
            if (tid >= off) incl += t;
        }
        lstart[tid] = incl - v;
    }
    __syncthreads();

    // A3: place register-held edges into compact LDS CSR
    for (int k = 0; k < npe; ++k) {
        uint_t p = pe[k];
        int d = (int)(p >> 25);
        int pos = atomicAdd(&lcur[d], 1);
        lcsr[lstart[d] + pos] = (int)(p & 0x01FFFFFF);
    }
    __syncthreads();

    // B: gather-mean. 2 passes x 4 nodes, round-robin -> 4 chains in flight.
    int r = lane >> 3, c = lane & 7;
#pragma unroll
    for (int half = 0; half < 2; ++half) {
        int ldbase = wave * 8 + half * 4;
        int dgs[4], bases[4];
        int maxdg = 0;
#pragma unroll
        for (int n = 0; n < 4; ++n) {
            dgs[n]   = ldeg[ldbase + n];
            bases[n] = lstart[ldbase + n];
            maxdg = (dgs[n] > maxdg) ? dgs[n] : maxdg;
        }

        float acc[4][8] = {};

        for (int j = 0; j < maxdg; j += 8) {
#pragma unroll
            for (int n = 0; n < 4; ++n) {
                if (j < dgs[n]) {                 // wave-uniform branch
                    int idx = j + r;
                    bool ok = idx < dgs[n];
                    int ii = ok ? idx : (dgs[n] - 1);
                    int s = lcsr[bases[n] + ii];
                    uint4 v = *reinterpret_cast<const uint4*>(feat + (size_t)s * 64 + c * 8);
                    if (ok) accum8(acc[n], v);
                }
            }
        }

#pragma unroll
        for (int n = 0; n < 4; ++n) {
#pragma unroll
            for (int i = 0; i < 8; ++i) {
                acc[n][i] += __shfl_xor(acc[n][i], 8, 64);
                acc[n][i] += __shfl_xor(acc[n][i], 16, 64);
                acc[n][i] += __shfl_xor(acc[n][i], 32, 64);
            }
            if (r == 0) {
                int ld = ldbase + n;
                float inv = 1.0f / fmaxf((float)dgs[n], 1.0f);
                uint4 o;
                o.x = pack2(acc[n][0] * inv, acc[n][1] * inv);
                o.y = pack2(acc[n][2] * inv, acc[n][3] * inv);
                o.z = pack2(acc[n][4] * inv, acc[n][5] * inv);
                o.w = pack2(acc[n][6] * inv, acc[n][7] * inv);
                int slot = c ^ (ld & 7);    // XOR-swizzle 16B chunks vs row
                *reinterpret_cast<uint4*>(&lmean[ld * 64 + slot * 8]) = o;
            }
        }
    }
    __syncthreads();
}

// ---------------------------------------------------------------------------
// Layer 1 fused: build+gather then h1 = relu(mean@W1l + self@W1r + b1).
// Dense: wave w -> M-tile w>>1, nt pair (w&1)*2.
// ---------------------------------------------------------------------------
__global__ __launch_bounds__(512) void agg_dense1(
    const ushort_t* __restrict__ xb, const int* __restrict__ gcur,
    const uint_t* __restrict__ bbuf, const uint4* __restrict__ wp,
    const float* __restrict__ bias, ushort_t* __restrict__ h1b)
{
    __shared__ int lcsr[CAPB];
    __shared__ int ldeg[BNODES];
    __shared__ int lstart[BNODES];
    __shared__ int lcur[BNODES];
    __shared__ ushort_t lmean[BNODES * 64];   // 8 KB

    build_and_gather(xb, gcur, bbuf, lcsr, ldeg, lstart, lcur, lmean);

    int tid = threadIdx.x;
    int wave = tid >> 6, lane = tid & 63;
    int node0 = blockIdx.x << BSHIFT;
    int q = lane >> 4, c16 = lane & 15;
    int mt  = wave >> 1;            // M-tile 0..3
    int nt0 = (wave & 1) * 2;       // nt pair
    int mrow = mt * 16 + c16;

    short8 am0 = *reinterpret_cast<const short8*>(&lmean[mrow * 64 + ((q ^ (mrow & 7)) << 3)]);
    short8 am1 = *reinterpret_cast<const short8*>(&lmean[mrow * 64 + (((q + 4) ^ (mrow & 7)) << 3)]);
    const ushort_t* sr = xb + (size_t)(node0 + mrow) * 64 + q * 8;
    short8 as0 = *reinterpret_cast<const short8*>(sr);
    short8 as1 = *reinterpret_cast<const short8*>(sr + 32);

#pragma unroll
    for (int t = 0; t < 2; ++t) {
        int nt = nt0 + t;
        short8 bl0 = *reinterpret_cast<const short8*>(&wp[nt * 128 + lane]);
        short8 bl1 = *reinterpret_cast<const short8*>(&wp[nt * 128 + 64 + lane]);
        short8 br0 = *reinterpret_cast<const short8*>(&wp[512 + nt * 128 + lane]);
        short8 br1 = *reinterpret_cast<const short8*>(&wp[512 + nt * 128 + 64 + lane]);
        float bv = bias[nt * 16 + c16];
        floatx4 a = (floatx4){bv, bv, bv, bv};
        a = __builtin_amdgcn_mfma_f32_16x16x32_bf16(am0, bl0, a, 0, 0, 0);
        a = __builtin_amdgcn_mfma_f32_16x16x32_bf16(am1, bl1, a, 0, 0, 0);
        a = __builtin_amdgcn_mfma_f32_16x16x32_bf16(as0, br0, a, 0, 0, 0);
        a = __builtin_amdgcn_mfma_f32_16x16x32_bf16(as1, br1, a, 0, 0, 0);
#pragma unroll
        for (int rr = 0; rr < 4; ++rr) {
            int node = node0 + mt * 16 + q * 4 + rr;
            h1b[(size_t)node * 64 + nt * 16 + c16] = f2b(fmaxf(a[rr], 0.0f));
        }
    }
}

// ---------------------------------------------------------------------------
// Layer 2 fused: build+gather(h1) then MFMA + log_softmax -> f32 out.
// Dense: waves 0..3 each own one M-tile (all 3 nt; softmax needs the row).
// ---------------------------------------------------------------------------
__global__ __launch_bounds__(512) void agg_dense2(
    const ushort_t* __restrict__ h1b, const int* __restrict__ gcur,
    const uint_t* __restrict__ bbuf, const uint4* __restrict__ wp,
    const float* __restrict__ bias, float* __restrict__ out)
{
    __shared__ int lcsr[CAPB];
    __shared__ int ldeg[BNODES];
    __shared__ int lstart[BNODES];
    __shared__ int lcur[BNODES];
    __shared__ ushort_t lmean[BNODES * 64];

    build_and_gather(h1b, gcur, bbuf, lcsr, ldeg, lstart, lcur, lmean);

    int tid = threadIdx.x;
    int wave = tid >> 6, lane = tid & 63;
    if (wave >= 4) return;

    int node0 = blockIdx.x << BSHIFT;
    int q = lane >> 4, c16 = lane & 15;
    int mt = wave;
    int mrow = mt * 16 + c16;
    bool v2ok = c16 < 8;    // tile 2 real cols: 32..39

    short8 am0 = *reinterpret_cast<const short8*>(&lmean[mrow * 64 + ((q ^ (mrow & 7)) << 3)]);
    short8 am1 = *reinterpret_cast<const short8*>(&lmean[mrow * 64 + (((q + 4) ^ (mrow & 7)) << 3)]);
    const ushort_t* sr = h1b + (size_t)(node0 + mrow) * 64 + q * 8;
    short8 as0 = *reinterpret_cast<const short8*>(sr);
    short8 as1 = *reinterpret_cast<const short8*>(sr + 32);

    floatx4 av[3];
#pragma unroll
    for (int nt = 0; nt < 3; ++nt) {
        short8 bl0 = *reinterpret_cast<const short8*>(&wp[1024 + nt * 128 + lane]);
        short8 bl1 = *reinterpret_cast<const short8*>(&wp[1024 + nt * 128 + 64 + lane]);
        short8 br0 = *reinterpret_cast<const short8*>(&wp[1408 + nt * 128 + lane]);
        short8 br1 = *reinterpret_cast<const short8*>(&wp[1408 + nt * 128 + 64 + lane]);
        int col = nt * 16 + c16;
        float bv = (col < OUT_CH) ? bias[col] : 0.0f;
        floatx4 a = (floatx4){bv, bv, bv, bv};
        a = __builtin_amdgcn_mfma_f32_16x16x32_bf16(am0, bl0, a, 0, 0, 0);
        a = __builtin_amdgcn_mfma_f32_16x16x32_bf16(am1, bl1, a, 0, 0, 0);
        a = __builtin_amdgcn_mfma_f32_16x16x32_bf16(as0, br0, a, 0, 0, 0);
        a = __builtin_amdgcn_mfma_f32_16x16x32_bf16(as1, br1, a, 0, 0, 0);
        av[nt] = a;
    }

    // fused log_softmax per node; row lives in the 16-lane col group
    // (shfl_xor 1,2,4,8 stays within the group; q fixed).
#pragma unroll
    for (int rr = 0; rr < 4; ++rr) {
        float v0 = av[0][rr];
        float v1 = av[1][rr];
        float v2 = av[2][rr];
        float mx = fmaxf(fmaxf(v0, v1), v2ok ? v2 : -1e30f);
        mx = fmaxf(mx, __shfl_xor(mx, 1, 64));
        mx = fmaxf(mx, __shfl_xor(mx, 2, 64));
        mx = fmaxf(mx, __shfl_xor(mx, 4, 64));
        mx = fmaxf(mx, __shfl_xor(mx, 8, 64));
        float e = __expf(v0 - mx) + __expf(v1 - mx) + (v2ok ? __expf(v2 - mx) : 0.0f);
        e += __shfl_xor(e, 1, 64);
        e += __shfl_xor(e, 2, 64);
        e += __shfl_xor(e, 4, 64);
        e += __shfl_xor(e, 8, 64);
        float ls = __logf(e);
        int node = node0 + mt * 16 + q * 4 + rr;
        if (node < N_NODES) {
            out[(size_t)node * OUT_CH + c16]      = v0 - mx - ls;
            out[(size_t)node * OUT_CH + 16 + c16] = v1 - mx - ls;
            if (v2ok)
                out[(size_t)node * OUT_CH + 32 + c16] = v2 - mx - ls;
        }
    }
}

extern "C" void kernel_launch(void* const* d_in, const int* in_sizes, int n_in,
                              void* d_out, int out_size, void* d_ws, size_t ws_size,
                              hipStream_t stream)
{
    const float* x   = (const float*)d_in[0];
    const int*   ei  = (const int*)d_in[1];     // (2, N_EDGES) int32
    const float* W1l = (const float*)d_in[2];
    const float* W1r = (const float*)d_in[3];
    const float* b1  = (const float*)d_in[4];
    const float* W2l = (const float*)d_in[5];
    const float* W2r = (const float*)d_in[6];
    const float* b2  = (const float*)d_in[7];
    float* out = (float*)d_out;

    const int* src = ei;
    const int* dst = ei + N_EDGES;

    // workspace layout
    int* gcur       = (int*)d_ws;                         // [2048] bucket cursors
    uint4* wp       = (uint4*)(gcur + 2048);              // [1792] frags, 28KB
    uint_t* bbuf    = (uint_t*)(wp + 1792);               // [NBUCK*CAPB] packed edges ~8.8MB
    ushort_t* xb    = (ushort_t*)(bbuf + (size_t)NBUCK * CAPB);  // [N_PAD*64] bf16
    ushort_t* h1b   = xb + (size_t)N_PAD * 64;            // [N_PAD*64] bf16
    // total ~= 0.04 + 8.8 + 25.6 MB ~= 34.5 MB

    const int n8 = N_NODES * 64 / 8;

    convert_kernel<<<(n8 + 255) / 256, 256, 0, stream>>>(x, xb, n8, gcur);
    pack_kernel<<<7, 256, 0, stream>>>(W1l, W1r, W2l, W2r, wp);

    const int sblocks = (N_EDGES + 256 * EPB - 1) / (256 * EPB);
    bucket_scatter<<<sblocks, 256, 0, stream>>>(src, dst, gcur, bbuf, N_EDGES);

    agg_dense1<<<NBUCK, 512, 0, stream>>>(xb, gcur, bbuf, wp, b1, h1b);
    agg_dense2<<<NBUCK, 512, 0, stream>>>(h1b, gcur, bbuf, wp, b2, out);
}

// Round 14
// 141.725 us; speedup vs baseline: 1.2926x; 1.2926x over previous
//
#include <hip/hip_runtime.h>
#include <hip/hip_bf16.h>

#define N_NODES 100000
#define N_PAD   100096      // 782 * 128
#define N_EDGES 1600000
#define OUT_CH  40

#define BSHIFT  6           // 64 nodes per bucket
#define BNODES  64
#define NBUCK   1563        // ceil(N_NODES / 64); covers nodes 0..100031
#define CAPB    1408        // edge capacity per bucket (mean 1024, +12 sigma)
#define EPB     32          // edges per thread in bucket_scatter

typedef unsigned short ushort_t;
typedef unsigned int uint_t;
typedef __attribute__((ext_vector_type(8))) short short8;   // 8 bf16 (4 VGPR)
typedef __attribute__((ext_vector_type(4))) float floatx4;  // MFMA C/D

__device__ inline float blo(uint_t u) { union { uint_t i; float f; } t; t.i = u << 16; return t.f; }
__device__ inline float bhi(uint_t u) { union { uint_t i; float f; } t; t.i = u & 0xffff0000u; return t.f; }
__device__ inline ushort_t f2b(float f) {
    __hip_bfloat16 h = __float2bfloat16(f);
    return *reinterpret_cast<ushort_t*>(&h);
}
__device__ inline uint_t pack2(float a, float b) {
    return (uint_t)f2b(a) | ((uint_t)f2b(b) << 16);
}

// ---------------------------------------------------------------------------
// f32 -> bf16 conversion, 8 elems/thread. Block 0 zeroes the bucket cursors.
// ---------------------------------------------------------------------------
__global__ __launch_bounds__(256) void convert_kernel(
    const float* __restrict__ in, ushort_t* __restrict__ out, int n8,
    int* __restrict__ gcur)
{
    if (blockIdx.x == 0) {
        for (int k = threadIdx.x; k < 2048; k += 256) gcur[k] = 0;
    }
    int i = blockIdx.x * 256 + threadIdx.x;
    if (i >= n8) return;
    const float4 a = *reinterpret_cast<const float4*>(in + (size_t)i * 8);
    const float4 b = *reinterpret_cast<const float4*>(in + (size_t)i * 8 + 4);
    uint4 o;
    o.x = pack2(a.x, a.y);
    o.y = pack2(a.z, a.w);
    o.z = pack2(b.x, b.y);
    o.w = pack2(b.z, b.w);
    *reinterpret_cast<uint4*>(out + (size_t)i * 8) = o;
}

// ---------------------------------------------------------------------------
// Weight pack into MFMA B-fragment layout (bf16). Bases (frag units):
// W1l=0, W1r=512, W2l=1024, W2r=1408 (layer-2 cols padded 40->48, zeros).
// ---------------------------------------------------------------------------
__global__ __launch_bounds__(256) void pack_kernel(
    const float* __restrict__ W1l, const float* __restrict__ W1r,
    const float* __restrict__ W2l, const float* __restrict__ W2r,
    uint4* __restrict__ wp)
{
    int i = blockIdx.x * 256 + threadIdx.x;
    if (i >= 1792) return;
    const float* W; int NC; int off;
    if (i < 512)       { W = W1l; NC = 64; off = i; }
    else if (i < 1024) { W = W1r; NC = 64; off = i - 512; }
    else if (i < 1408) { W = W2l; NC = 40; off = i - 1024; }
    else               { W = W2r; NC = 40; off = i - 1408; }
    int l   = off & 63;
    int kc  = (off >> 6) & 1;
    int nt  = off >> 7;
    int k0  = kc * 32 + ((l >> 4) * 8);
    int col = nt * 16 + (l & 15);
    float v[8];
#pragma unroll
    for (int j = 0; j < 8; ++j)
        v[j] = (col < NC) ? W[(k0 + j) * NC + col] : 0.0f;
    uint4 o;
    o.x = pack2(v[0], v[1]);
    o.y = pack2(v[2], v[3]);
    o.z = pack2(v[4], v[5]);
    o.w = pack2(v[6], v[7]);
    wp[i] = o;
}

// ---------------------------------------------------------------------------
// Partition edges into NBUCK dst-range buckets. Randomness confined to LDS
// histogram atomics; one global atomic per (block,bucket); packed edges:
// src (25b) | local-dst << 25.
// ---------------------------------------------------------------------------
__global__ __launch_bounds__(256) void bucket_scatter(
    const int* __restrict__ src, const int* __restrict__ dst,
    int* __restrict__ gcur, uint_t* __restrict__ bbuf, int n)
{
    __shared__ int lcnt[NBUCK];
    __shared__ int lbase[NBUCK];
    for (int i = threadIdx.x; i < NBUCK; i += 256) lcnt[i] = 0;
    __syncthreads();

    int e0 = blockIdx.x * (256 * EPB) + threadIdx.x;
    int b[EPB], lp[EPB], s[EPB];
#pragma unroll
    for (int u = 0; u < EPB; ++u) {
        int e = e0 + u * 256;
        if (e < n) {
            int d = dst[e];
            s[u] = src[e];
            b[u] = d >> BSHIFT;
            lp[u] = atomicAdd(&lcnt[b[u]], 1);        // pos fits 24 bits
            lp[u] |= (d & (BNODES - 1)) << 24;        // local node in bits 24..29
        } else {
            b[u] = -1;
        }
    }
    __syncthreads();
    for (int i = threadIdx.x; i < NBUCK; i += 256) {
        int c = lcnt[i];
        lbase[i] = (c > 0) ? atomicAdd(&gcur[i], c) : 0;
    }
    __syncthreads();
#pragma unroll
    for (int u = 0; u < EPB; ++u) {
        if (b[u] >= 0) {
            int pos = lbase[b[u]] + (lp[u] & 0x00FFFFFF);
            uint_t ldst = ((uint_t)lp[u]) >> 24;
            if (pos < CAPB)
                bbuf[(size_t)b[u] * CAPB + pos] = (uint_t)s[u] | (ldst << 25);
        }
    }
}

// ---------------------------------------------------------------------------
// Fused per-bucket kernel core (512 threads / 8 waves) -- R12 structure:
//   A) register-held CSR build (LDS histogram + wave-0 scan + place).
//   B) gather: 8 nodes per wave SEQUENTIAL, 8 rows per VMEM instr
//      (r=lane>>3 row, c=lane&7 16B chunk), up to 4 loads in flight via
//      the unrolled 32/16/8-row ladder.
//   C) mean -> swizzled LDS; dense via MFMA from LDS mean + prefetched self.
// ---------------------------------------------------------------------------
__device__ inline void accum8(float* acc, uint4 v) {
    acc[0] += blo(v.x); acc[1] += bhi(v.x);
    acc[2] += blo(v.y); acc[3] += bhi(v.y);
    acc[4] += blo(v.z); acc[5] += bhi(v.z);
    acc[6] += blo(v.w); acc[7] += bhi(v.w);
}

__device__ inline void build_and_gather(
    const ushort_t* __restrict__ feat, const int* __restrict__ gcur,
    const uint_t* __restrict__ bbuf,
    int* lcsr, int* ldeg, int* lstart, int* lcur, ushort_t* lmean)
{
    int b = blockIdx.x, tid = threadIdx.x;
    int wave = tid >> 6, lane = tid & 63;

    if (tid < BNODES) { ldeg[tid] = 0; lcur[tid] = 0; }
    __syncthreads();

    int ne = gcur[b];
    if (ne > CAPB) ne = CAPB;

    // A1: read edges into registers (<=3 each), histogram degrees in LDS
    uint_t pe[3];
    int npe = 0;
    for (int i = tid; i < ne; i += 512) {
        uint_t p = bbuf[(size_t)b * CAPB + i];
        pe[npe++] = p;
        atomicAdd(&ldeg[p >> 25], 1);
    }
    __syncthreads();

    // A2: wave-0 exclusive scan over 64 degree counts
    if (tid < 64) {
        int v = ldeg[tid];
        int incl = v;
#pragma unroll
        for (int off = 1; off < 64; off <<= 1) {
            int t = __shfl_up(incl, off, 64);
            if (tid >= off) incl += t;
        }
        lstart[tid] = incl - v;
    }
    __syncthreads();

    // A3: place register-held edges into compact LDS CSR
    for (int k = 0; k < npe; ++k) {
        uint_t p = pe[k];
        int d = (int)(p >> 25);
        int pos = atomicAdd(&lcur[d], 1);
        lcsr[lstart[d] + pos] = (int)(p & 0x01FFFFFF);
    }
    __syncthreads();

    // B: gather-mean, 8 nodes per wave
    int r = lane >> 3, c = lane & 7;
    for (int ld = wave * 8; ld < wave * 8 + 8; ++ld) {
        int dg   = ldeg[ld];
        int base = lstart[ld];

        float acc[8] = {0, 0, 0, 0, 0, 0, 0, 0};

        int j = 0;
        for (; j + 32 <= dg; j += 32) {
            int s0 = lcsr[base + j + r];
            int s1 = lcsr[base + j + 8 + r];
            int s2 = lcsr[base + j + 16 + r];
            int s3 = lcsr[base + j + 24 + r];
            uint4 v0 = *reinterpret_cast<const uint4*>(feat + (size_t)s0 * 64 + c * 8);
            uint4 v1 = *reinterpret_cast<const uint4*>(feat + (size_t)s1 * 64 + c * 8);
            uint4 v2 = *reinterpret_cast<const uint4*>(feat + (size_t)s2 * 64 + c * 8);
            uint4 v3 = *reinterpret_cast<const uint4*>(feat + (size_t)s3 * 64 + c * 8);
            accum8(acc, v0); accum8(acc, v1); accum8(acc, v2); accum8(acc, v3);
        }
        if (j + 16 <= dg) {
            int s0 = lcsr[base + j + r];
            int s1 = lcsr[base + j + 8 + r];
            uint4 v0 = *reinterpret_cast<const uint4*>(feat + (size_t)s0 * 64 + c * 8);
            uint4 v1 = *reinterpret_cast<const uint4*>(feat + (size_t)s1 * 64 + c * 8);
            accum8(acc, v0); accum8(acc, v1);
            j += 16;
        }
        if (j + 8 <= dg) {
            int s = lcsr[base + j + r];
            uint4 v = *reinterpret_cast<const uint4*>(feat + (size_t)s * 64 + c * 8);
            accum8(acc, v);
            j += 8;
        }
        if (r < dg - j) {
            int s = lcsr[base + j + r];
            uint4 v = *reinterpret_cast<const uint4*>(feat + (size_t)s * 64 + c * 8);
            accum8(acc, v);
        }

#pragma unroll
        for (int i = 0; i < 8; ++i) {
            acc[i] += __shfl_xor(acc[i], 8, 64);
            acc[i] += __shfl_xor(acc[i], 16, 64);
            acc[i] += __shfl_xor(acc[i], 32, 64);
        }

        if (r == 0) {
            float inv = 1.0f / fmaxf((float)dg, 1.0f);
            uint4 o;
            o.x = pack2(acc[0] * inv, acc[1] * inv);
            o.y = pack2(acc[2] * inv, acc[3] * inv);
            o.z = pack2(acc[4] * inv, acc[5] * inv);
            o.w = pack2(acc[6] * inv, acc[7] * inv);
            int slot = c ^ (ld & 7);    // XOR-swizzle 16B chunks vs row
            *reinterpret_cast<uint4*>(&lmean[ld * 64 + slot * 8]) = o;
        }
    }
    __syncthreads();
}

// ---------------------------------------------------------------------------
// Layer 1 fused: build+gather then h1 = relu(mean@W1l + self@W1r + b1).
// Self rows + bias are PREFETCHED before build_and_gather: the global-load
// latency hides under the ~50us of build+gather instead of serializing
// after the last barrier. Dense: wave w -> M-tile w>>1, nt pair (w&1)*2.
// ---------------------------------------------------------------------------
__global__ __launch_bounds__(512) void agg_dense1(
    const ushort_t* __restrict__ xb, const int* __restrict__ gcur,
    const uint_t* __restrict__ bbuf, const uint4* __restrict__ wp,
    const float* __restrict__ bias, ushort_t* __restrict__ h1b)
{
    __shared__ int lcsr[CAPB];
    __shared__ int ldeg[BNODES];
    __shared__ int lstart[BNODES];
    __shared__ int lcur[BNODES];
    __shared__ ushort_t lmean[BNODES * 64];   // 8 KB

    int tid = threadIdx.x;
    int wave = tid >> 6, lane = tid & 63;
    int node0 = blockIdx.x << BSHIFT;
    int q = lane >> 4, c16 = lane & 15;
    int mt  = wave >> 1;            // M-tile 0..3
    int nt0 = (wave & 1) * 2;       // nt pair
    int mrow = mt * 16 + c16;

    // prefetch self rows + bias (independent of gather)
    const ushort_t* sr = xb + (size_t)(node0 + mrow) * 64 + q * 8;
    short8 as0 = *reinterpret_cast<const short8*>(sr);
    short8 as1 = *reinterpret_cast<const short8*>(sr + 32);
    float bv0 = bias[nt0 * 16 + c16];
    float bv1 = bias[(nt0 + 1) * 16 + c16];

    build_and_gather(xb, gcur, bbuf, lcsr, ldeg, lstart, lcur, lmean);

    short8 am0 = *reinterpret_cast<const short8*>(&lmean[mrow * 64 + ((q ^ (mrow & 7)) << 3)]);
    short8 am1 = *reinterpret_cast<const short8*>(&lmean[mrow * 64 + (((q + 4) ^ (mrow & 7)) << 3)]);

#pragma unroll
    for (int t = 0; t < 2; ++t) {
        int nt = nt0 + t;
        short8 bl0 = *reinterpret_cast<const short8*>(&wp[nt * 128 + lane]);
        short8 bl1 = *reinterpret_cast<const short8*>(&wp[nt * 128 + 64 + lane]);
        short8 br0 = *reinterpret_cast<const short8*>(&wp[512 + nt * 128 + lane]);
        short8 br1 = *reinterpret_cast<const short8*>(&wp[512 + nt * 128 + 64 + lane]);
        float bv = t ? bv1 : bv0;
        floatx4 a = (floatx4){bv, bv, bv, bv};
        a = __builtin_amdgcn_mfma_f32_16x16x32_bf16(am0, bl0, a, 0, 0, 0);
        a = __builtin_amdgcn_mfma_f32_16x16x32_bf16(am1, bl1, a, 0, 0, 0);
        a = __builtin_amdgcn_mfma_f32_16x16x32_bf16(as0, br0, a, 0, 0, 0);
        a = __builtin_amdgcn_mfma_f32_16x16x32_bf16(as1, br1, a, 0, 0, 0);
#pragma unroll
        for (int rr = 0; rr < 4; ++rr) {
            int node = node0 + mt * 16 + q * 4 + rr;
            h1b[(size_t)node * 64 + nt * 16 + c16] = f2b(fmaxf(a[rr], 0.0f));
        }
    }
}

// ---------------------------------------------------------------------------
// Layer 2 fused: build+gather(h1) then MFMA + log_softmax -> f32 out.
// Self rows + bias prefetched. Dense: waves 0..3 each own one M-tile.
// ---------------------------------------------------------------------------
__global__ __launch_bounds__(512) void agg_dense2(
    const ushort_t* __restrict__ h1b, const int* __restrict__ gcur,
    const uint_t* __restrict__ bbuf, const uint4* __restrict__ wp,
    const float* __restrict__ bias, float* __restrict__ out)
{
    __shared__ int lcsr[CAPB];
    __shared__ int ldeg[BNODES];
    __shared__ int lstart[BNODES];
    __shared__ int lcur[BNODES];
    __shared__ ushort_t lmean[BNODES * 64];

    int tid = threadIdx.x;
    int wave = tid >> 6, lane = tid & 63;
    int node0 = blockIdx.x << BSHIFT;
    int q = lane >> 4, c16 = lane & 15;
    int mt = wave & 3;
    int mrow = mt * 16 + c16;
    bool v2ok = c16 < 8;    // tile 2 real cols: 32..39

    // prefetch self rows + bias (waves 0..3 only use them, but loads are cheap)
    const ushort_t* sr = h1b + (size_t)(node0 + mrow) * 64 + q * 8;
    short8 as0 = *reinterpret_cast<const short8*>(sr);
    short8 as1 = *reinterpret_cast<const short8*>(sr + 32);
    float bvp[3];
#pragma unroll
    for (int nt = 0; nt < 3; ++nt) {
        int col = nt * 16 + c16;
        bvp[nt] = (col < OUT_CH) ? bias[col] : 0.0f;
    }

    build_and_gather(h1b, gcur, bbuf, lcsr, ldeg, lstart, lcur, lmean);

    if (wave >= 4) return;

    short8 am0 = *reinterpret_cast<const short8*>(&lmean[mrow * 64 + ((q ^ (mrow & 7)) << 3)]);
    short8 am1 = *reinterpret_cast<const short8*>(&lmean[mrow * 64 + (((q + 4) ^ (mrow & 7)) << 3)]);

    floatx4 av[3];
#pragma unroll
    for (int nt = 0; nt < 3; ++nt) {
        short8 bl0 = *reinterpret_cast<const short8*>(&wp[1024 + nt * 128 + lane]);
        short8 bl1 = *reinterpret_cast<const short8*>(&wp[1024 + nt * 128 + 64 + lane]);
        short8 br0 = *reinterpret_cast<const short8*>(&wp[1408 + nt * 128 + lane]);
        short8 br1 = *reinterpret_cast<const short8*>(&wp[1408 + nt * 128 + 64 + lane]);
        floatx4 a = (floatx4){bvp[nt], bvp[nt], bvp[nt], bvp[nt]};
        a = __builtin_amdgcn_mfma_f32_16x16x32_bf16(am0, bl0, a, 0, 0, 0);
        a = __builtin_amdgcn_mfma_f32_16x16x32_bf16(am1, bl1, a, 0, 0, 0);
        a = __builtin_amdgcn_mfma_f32_16x16x32_bf16(as0, br0, a, 0, 0, 0);
        a = __builtin_amdgcn_mfma_f32_16x16x32_bf16(as1, br1, a, 0, 0, 0);
        av[nt] = a;
    }

    // fused log_softmax per node; row lives in the 16-lane col group
    // (shfl_xor 1,2,4,8 stays within the group; q fixed).
#pragma unroll
    for (int rr = 0; rr < 4; ++rr) {
        float v0 = av[0][rr];
        float v1 = av[1][rr];
        float v2 = av[2][rr];
        float mx = fmaxf(fmaxf(v0, v1), v2ok ? v2 : -1e30f);
        mx = fmaxf(mx, __shfl_xor(mx, 1, 64));
        mx = fmaxf(mx, __shfl_xor(mx, 2, 64));
        mx = fmaxf(mx, __shfl_xor(mx, 4, 64));
        mx = fmaxf(mx, __shfl_xor(mx, 8, 64));
        float e = __expf(v0 - mx) + __expf(v1 - mx) + (v2ok ? __expf(v2 - mx) : 0.0f);
        e += __shfl_xor(e, 1, 64);
        e += __shfl_xor(e, 2, 64);
        e += __shfl_xor(e, 4, 64);
        e += __shfl_xor(e, 8, 64);
        float ls = __logf(e);
        int node = node0 + mt * 16 + q * 4 + rr;
        if (node < N_NODES) {
            out[(size_t)node * OUT_CH + c16]      = v0 - mx - ls;
            out[(size_t)node * OUT_CH + 16 + c16] = v1 - mx - ls;
            if (v2ok)
                out[(size_t)node * OUT_CH + 32 + c16] = v2 - mx - ls;
        }
    }
}

extern "C" void kernel_launch(void* const* d_in, const int* in_sizes, int n_in,
                              void* d_out, int out_size, void* d_ws, size_t ws_size,
                              hipStream_t stream)
{
    const float* x   = (const float*)d_in[0];
    const int*   ei  = (const int*)d_in[1];     // (2, N_EDGES) int32
    const float* W1l = (const float*)d_in[2];
    const float* W1r = (const float*)d_in[3];
    const float* b1  = (const float*)d_in[4];
    const float* W2l = (const float*)d_in[5];
    const float* W2r = (const float*)d_in[6];
    const float* b2  = (const float*)d_in[7];
    float* out = (float*)d_out;

    const int* src = ei;
    const int* dst = ei + N_EDGES;

    // workspace layout
    int* gcur       = (int*)d_ws;                         // [2048] bucket cursors
    uint4* wp       = (uint4*)(gcur + 2048);              // [1792] frags, 28KB
    uint_t* bbuf    = (uint_t*)(wp + 1792);               // [NBUCK*CAPB] packed edges ~8.8MB
    ushort_t* xb    = (ushort_t*)(bbuf + (size_t)NBUCK * CAPB);  // [N_PAD*64] bf16
    ushort_t* h1b   = xb + (size_t)N_PAD * 64;            // [N_PAD*64] bf16
    // total ~= 0.04 + 8.8 + 25.6 MB ~= 34.5 MB

    const int n8 = N_NODES * 64 / 8;

    convert_kernel<<<(n8 + 255) / 256, 256, 0, stream>>>(x, xb, n8, gcur);
    pack_kernel<<<7, 256, 0, stream>>>(W1l, W1r, W2l, W2r, wp);

    const int sblocks = (N_EDGES + 256 * EPB - 1) / (256 * EPB);
    bucket_scatter<<<sblocks, 256, 0, stream>>>(src, dst, gcur, bbuf, N_EDGES);

    agg_dense1<<<NBUCK, 512, 0, stream>>>(xb, gcur, bbuf, wp, b1, h1b);
    agg_dense2<<<NBUCK, 512, 0, stream>>>(h1b, gcur, bbuf, wp, b2, out);
}